// Round 1
// baseline (37.964 us; speedup 1.0000x reference)
//
#include <hip/hip_runtime.h>

// QAoutputBlock: per-batch banded-outer-product argmax.
// out1[b] = argmax_i max(0, max_{j in [i, i+limit]} x1[b,i]*x2[b,j])
// out2[b] = argmax_j max(0, max_{i in [j-limit, j]} x1[b,i]*x2[b,j])
// Output layout: out[0..B-1] = out1, out[B..2B-1] = out2 (float32 indices).

constexpr int S_CT = 2048;
constexpr int NT = 256;

__global__ __launch_bounds__(NT) void qa_argmax_kernel(
    const float* __restrict__ x1, const float* __restrict__ x2,
    const int* __restrict__ limit_ptr, float* __restrict__ out, int B) {
    const int b = blockIdx.x;
    const int tid = threadIdx.x;
    const int limit = limit_ptr[0];

    __shared__ float s1[S_CT];
    __shared__ float s2[S_CT];
    const float* x1b = x1 + (size_t)b * S_CT;
    const float* x2b = x2 + (size_t)b * S_CT;
    for (int i = tid; i < S_CT; i += NT) {
        s1[i] = x1b[i];
        s2[i] = x2b[i];
    }
    __syncthreads();

    // Per-thread banded maxes. i strictly increases within a thread, so
    // strict '>' keeps the first (lowest) index on fp-equal ties.
    float best1 = -1.0f; int bi1 = 0;   // row path (values are >= 0 due to floor)
    float best2 = -1.0f; int bi2 = 0;   // col path
    for (int i = tid; i < S_CT; i += NT) {
        // row i: j in [i, min(i+limit, S-1)]
        float a = s1[i];
        float m = 0.0f;                  // zero floor from off-band entries
        int jend = min(i + limit, S_CT - 1);
        #pragma unroll 4
        for (int j = i; j <= jend; ++j) m = fmaxf(m, a * s2[j]);
        if (m > best1) { best1 = m; bi1 = i; }

        // col i: k in [max(i-limit,0), i]
        float c = s2[i];
        float m2 = 0.0f;
        int k0 = max(i - limit, 0);
        #pragma unroll 4
        for (int k = k0; k <= i; ++k) m2 = fmaxf(m2, s1[k] * c);
        if (m2 > best2) { best2 = m2; bi2 = i; }
    }

    // Block argmax reduction, lower-index wins on ties (jnp.argmax semantics).
    __shared__ float sv[NT];
    __shared__ int   si[NT];

    sv[tid] = best1; si[tid] = bi1;
    __syncthreads();
    for (int off = NT / 2; off > 0; off >>= 1) {
        if (tid < off) {
            float v = sv[tid + off]; int ix = si[tid + off];
            if (v > sv[tid] || (v == sv[tid] && ix < si[tid])) { sv[tid] = v; si[tid] = ix; }
        }
        __syncthreads();
    }
    if (tid == 0) out[b] = (float)si[0];
    __syncthreads();

    sv[tid] = best2; si[tid] = bi2;
    __syncthreads();
    for (int off = NT / 2; off > 0; off >>= 1) {
        if (tid < off) {
            float v = sv[tid + off]; int ix = si[tid + off];
            if (v > sv[tid] || (v == sv[tid] && ix < si[tid])) { sv[tid] = v; si[tid] = ix; }
        }
        __syncthreads();
    }
    if (tid == 0) out[B + b] = (float)si[0];
}

extern "C" void kernel_launch(void* const* d_in, const int* in_sizes, int n_in,
                              void* d_out, int out_size, void* d_ws, size_t ws_size,
                              hipStream_t stream) {
    const float* x1 = (const float*)d_in[0];
    const float* x2 = (const float*)d_in[1];
    const int* limit = (const int*)d_in[2];
    float* out = (float*)d_out;
    const int B = in_sizes[0] / S_CT;  // 32

    qa_argmax_kernel<<<B, NT, 0, stream>>>(x1, x2, limit, out, B);
}

// Round 2
// 15.609 us; speedup vs baseline: 2.4322x; 2.4322x over previous
//
#include <hip/hip_runtime.h>

// QAoutputBlock: per-batch banded-outer-product argmax, 2-kernel version.
// Kernel 1: 256 blocks (B=32 batches x 8 chunks), one row + one col per thread,
//           global loads (coalesced per j-offset), block (val,idx) argmax -> ws.
// Kernel 2: one tiny block; thread t combines the 8 chunk-partials for
//           (path = t/B, batch = t%B) in ascending chunk order (tie: lower idx).
// Output: out[0..B-1] = out1 (row argmax), out[B..2B-1] = out2 (col argmax).

constexpr int S_CT = 2048;
constexpr int NT = 256;
constexpr int CHUNKS = S_CT / NT;  // 8

__global__ __launch_bounds__(NT) void qa_partial_kernel(
    const float* __restrict__ x1, const float* __restrict__ x2,
    const int* __restrict__ limit_ptr, float2* __restrict__ ws, int B) {
    const int blk = blockIdx.x;
    const int b = blk / CHUNKS;
    const int chunk = blk % CHUNKS;
    const int tid = threadIdx.x;
    const int i = chunk * NT + tid;
    const int limit = limit_ptr[0];
    const float* __restrict__ x1b = x1 + (size_t)b * S_CT;
    const float* __restrict__ x2b = x2 + (size_t)b * S_CT;

    // Row i: max(0, max_{j in [i, min(i+limit,S-1)]} x1[i]*x2[j])
    float a = x1b[i];
    float m1 = 0.0f;
    const int jend = min(i + limit, S_CT - 1);
    #pragma unroll 4
    for (int j = i; j <= jend; ++j) m1 = fmaxf(m1, a * x2b[j]);

    // Col i: max(0, max_{k in [max(i-limit,0), i]} x1[k]*x2[i])
    float c = x2b[i];
    float m2 = 0.0f;
    const int k0 = max(i - limit, 0);
    #pragma unroll 4
    for (int k = k0; k <= i; ++k) m2 = fmaxf(m2, x1b[k] * c);

    // Block argmax reduction for both paths, lower-index wins on ties.
    __shared__ float sv1[NT]; __shared__ int si1[NT];
    __shared__ float sv2[NT]; __shared__ int si2[NT];
    sv1[tid] = m1; si1[tid] = i;
    sv2[tid] = m2; si2[tid] = i;
    __syncthreads();
    for (int off = NT / 2; off > 0; off >>= 1) {
        if (tid < off) {
            float v = sv1[tid + off]; int ix = si1[tid + off];
            if (v > sv1[tid] || (v == sv1[tid] && ix < si1[tid])) { sv1[tid] = v; si1[tid] = ix; }
            v = sv2[tid + off]; ix = si2[tid + off];
            if (v > sv2[tid] || (v == sv2[tid] && ix < si2[tid])) { sv2[tid] = v; si2[tid] = ix; }
        }
        __syncthreads();
    }
    if (tid == 0) {
        ws[blk]              = make_float2(sv1[0], (float)si1[0]);  // row partial
        ws[B * CHUNKS + blk] = make_float2(sv2[0], (float)si2[0]);  // col partial
    }
}

__global__ __launch_bounds__(64) void qa_combine_kernel(
    const float2* __restrict__ ws, float* __restrict__ out, int B) {
    const int t = threadIdx.x;
    if (t >= 2 * B) return;
    const int path = t / B;  // 0 = rows (out1), 1 = cols (out2)
    const int b = t % B;
    const float2* p = ws + (size_t)path * B * CHUNKS + (size_t)b * CHUNKS;
    float best = -1.0f; int bi = 0;
    #pragma unroll
    for (int c = 0; c < CHUNKS; ++c) {
        float2 v = p[c];
        if (v.x > best) { best = v.x; bi = (int)v.y; }  // ascending chunks: strict > keeps lowest index
    }
    out[(size_t)path * B + b] = (float)bi;
}

extern "C" void kernel_launch(void* const* d_in, const int* in_sizes, int n_in,
                              void* d_out, int out_size, void* d_ws, size_t ws_size,
                              hipStream_t stream) {
    const float* x1 = (const float*)d_in[0];
    const float* x2 = (const float*)d_in[1];
    const int* limit = (const int*)d_in[2];
    float* out = (float*)d_out;
    float2* ws = (float2*)d_ws;
    const int B = in_sizes[0] / S_CT;  // 32

    qa_partial_kernel<<<B * CHUNKS, NT, 0, stream>>>(x1, x2, limit, ws, B);
    qa_combine_kernel<<<1, 64, 0, stream>>>(ws, out, B);
}

// Round 3
// 13.896 us; speedup vs baseline: 2.7320x; 1.1233x over previous
//
#include <hip/hip_runtime.h>

// QAoutputBlock: per-batch banded-outer-product argmax, single fused kernel.
// Grid = B*2 blocks: block (b, path) computes one full argmax over 2048 positions.
//   path 0: out1[b] = argmax_i max(0, max_{d in [0,limit], i+d<S} x1[b,i]*x2[b,i+d])
//   path 1: out2[b] = argmax_i max(0, max_{d in [0,limit], i-d>=0} x1[b,i-d]*x2[b,i])
// Output: out[0..B-1] = out1, out[B..2B-1] = out2 (float32 indices).

constexpr int S_CT = 2048;
constexpr int NT = 256;
constexpr int PPT = S_CT / NT;  // 8 positions per thread

__global__ __launch_bounds__(NT) void qa_fused_kernel(
    const float* __restrict__ x1, const float* __restrict__ x2,
    const int* __restrict__ limit_ptr, float* __restrict__ out, int B) {
    const int blk = blockIdx.x;
    const int b = blk >> 1;
    const int path = blk & 1;
    const int tid = threadIdx.x;
    const int limit = limit_ptr[0];
    const float* __restrict__ xa = x1 + (size_t)b * S_CT;
    const float* __restrict__ xb = x2 + (size_t)b * S_CT;

    float m[PPT];
    float w[PPT];
    #pragma unroll
    for (int r = 0; r < PPT; ++r) m[r] = 0.0f;

    if (path == 0) {
        // rows: w = x1[i] fixed, scan x2[i+d]
        #pragma unroll
        for (int r = 0; r < PPT; ++r) w[r] = xa[r * NT + tid];
        for (int d = 0; d <= limit; ++d) {
            #pragma unroll
            for (int r = 0; r < PPT; ++r) {
                int j = r * NT + tid + d;
                if (r < PPT - 1 || j < S_CT)  // only last sub-block can overflow
                    m[r] = fmaxf(m[r], w[r] * xb[j]);
            }
        }
    } else {
        // cols: w = x2[i] fixed, scan x1[i-d]
        #pragma unroll
        for (int r = 0; r < PPT; ++r) w[r] = xb[r * NT + tid];
        for (int d = 0; d <= limit; ++d) {
            #pragma unroll
            for (int r = 0; r < PPT; ++r) {
                int k = r * NT + tid - d;
                if (r > 0 || k >= 0)          // only first sub-block can underflow
                    m[r] = fmaxf(m[r], xa[k] * w[r]);
            }
        }
    }

    // Per-thread argmax over its 8 ascending positions (strict > keeps lowest index).
    float best = -1.0f; int bi = 0;
    #pragma unroll
    for (int r = 0; r < PPT; ++r) {
        int i = r * NT + tid;
        if (m[r] > best) { best = m[r]; bi = i; }
    }

    // Block argmax reduction, lower-index wins on fp-equal ties.
    __shared__ float sv[NT];
    __shared__ int   si[NT];
    sv[tid] = best; si[tid] = bi;
    __syncthreads();
    for (int off = NT / 2; off > 0; off >>= 1) {
        if (tid < off) {
            float v = sv[tid + off]; int ix = si[tid + off];
            if (v > sv[tid] || (v == sv[tid] && ix < si[tid])) { sv[tid] = v; si[tid] = ix; }
        }
        __syncthreads();
    }
    if (tid == 0) out[(size_t)path * B + b] = (float)si[0];
}

extern "C" void kernel_launch(void* const* d_in, const int* in_sizes, int n_in,
                              void* d_out, int out_size, void* d_ws, size_t ws_size,
                              hipStream_t stream) {
    const float* x1 = (const float*)d_in[0];
    const float* x2 = (const float*)d_in[1];
    const int* limit = (const int*)d_in[2];
    float* out = (float*)d_out;
    const int B = in_sizes[0] / S_CT;  // 32

    qa_fused_kernel<<<B * 2, NT, 0, stream>>>(x1, x2, limit, out, B);
}

// Round 4
// 9.857 us; speedup vs baseline: 3.8514x; 1.4097x over previous
//
#include <hip/hip_runtime.h>

// QAoutputBlock: per-batch banded-outer-product argmax, single kernel.
// Grid = B*2 blocks: block (b, path).
//   path 0: out1[b] = argmax_i max(0, max_{d in [0,L], i+d<S} x1[b,i]*x2[b,i+d])
//   path 1: out2[b] = argmax_i max(0, max_{d in [0,L], i-d>=0} x1[b,i-d]*x2[b,i])
// Fast path (L==30, compile-time): each thread owns 8 CONSECUTIVE positions;
// loads its 40-float window via 10x float4 into registers (OOB -> 0.0, neutral
// since running max >= 0), fully-unrolled static-index 8x31 mul+fmax, then
// shfl_xor (val,idx) butterfly + 1-barrier cross-wave combine.
// Output: out[0..B-1] = out1, out[B..2B-1] = out2 (float32 indices).

constexpr int S_CT = 2048;
constexpr int NT = 256;
constexpr int PPT = S_CT / NT;  // 8
constexpr int L_FAST = 30;

__global__ __launch_bounds__(NT) void qa_fused_kernel(
    const float* __restrict__ x1, const float* __restrict__ x2,
    const int* __restrict__ limit_ptr, float* __restrict__ out, int B) {
    const int blk = blockIdx.x;
    const int b = blk >> 1;
    const int path = blk & 1;
    const int tid = threadIdx.x;
    const int limit = limit_ptr[0];
    const float* __restrict__ xa = x1 + (size_t)b * S_CT;
    const float* __restrict__ xb = x2 + (size_t)b * S_CT;

    float best = -1.0f;
    int bi = 0;

    if (limit == L_FAST) {
        // ---------- fast path: compile-time window, all-register ----------
        const int base = tid * PPT;  // 8 consecutive positions, 32B-aligned
        float w[PPT], v[40], m[PPT];
        #pragma unroll
        for (int r = 0; r < PPT; ++r) m[r] = 0.0f;

        if (path == 0) {
            // rows: w = x1[base+r]; window = x2[base .. base+37]
            float4 w0 = *(const float4*)(xa + base);
            float4 w1 = *(const float4*)(xa + base + 4);
            w[0]=w0.x; w[1]=w0.y; w[2]=w0.z; w[3]=w0.w;
            w[4]=w1.x; w[5]=w1.y; w[6]=w1.z; w[7]=w1.w;
            #pragma unroll
            for (int q = 0; q < 10; ++q) {
                int off = base + 4 * q;
                float4 t = *(const float4*)(xb + (off <= S_CT - 4 ? off : S_CT - 4));
                v[4*q+0] = (off + 0 < S_CT) ? t.x : 0.0f;
                v[4*q+1] = (off + 1 < S_CT) ? t.y : 0.0f;
                v[4*q+2] = (off + 2 < S_CT) ? t.z : 0.0f;
                v[4*q+3] = (off + 3 < S_CT) ? t.w : 0.0f;
            }
            #pragma unroll
            for (int r = 0; r < PPT; ++r)
                #pragma unroll
                for (int d = 0; d <= L_FAST; ++d)
                    m[r] = fmaxf(m[r], w[r] * v[r + d]);
        } else {
            // cols: w = x2[base+r]; window = x1[base-32 .. base+7]
            float4 w0 = *(const float4*)(xb + base);
            float4 w1 = *(const float4*)(xb + base + 4);
            w[0]=w0.x; w[1]=w0.y; w[2]=w0.z; w[3]=w0.w;
            w[4]=w1.x; w[5]=w1.y; w[6]=w1.z; w[7]=w1.w;
            #pragma unroll
            for (int q = 0; q < 10; ++q) {
                int off = base - 32 + 4 * q;
                float4 t = *(const float4*)(xa + (off >= 0 ? off : 0));
                v[4*q+0] = (off + 0 >= 0) ? t.x : 0.0f;
                v[4*q+1] = (off + 1 >= 0) ? t.y : 0.0f;
                v[4*q+2] = (off + 2 >= 0) ? t.z : 0.0f;
                v[4*q+3] = (off + 3 >= 0) ? t.w : 0.0f;
            }
            // position i=base+r reads x1[k], k in [i-30, i] -> v[r+2 .. r+32]
            #pragma unroll
            for (int r = 0; r < PPT; ++r)
                #pragma unroll
                for (int d = 0; d <= L_FAST; ++d)
                    m[r] = fmaxf(m[r], w[r] * v[r + 2 + d]);
        }
        // per-thread argmax, ascending positions, strict > keeps lowest index
        #pragma unroll
        for (int r = 0; r < PPT; ++r)
            if (m[r] > best) { best = m[r]; bi = base + r; }
    } else {
        // ---------- generic fallback: runtime limit (R2 structure) ----------
        float m[PPT];
        float w[PPT];
        #pragma unroll
        for (int r = 0; r < PPT; ++r) m[r] = 0.0f;
        if (path == 0) {
            #pragma unroll
            for (int r = 0; r < PPT; ++r) w[r] = xa[r * NT + tid];
            for (int d = 0; d <= limit; ++d) {
                #pragma unroll
                for (int r = 0; r < PPT; ++r) {
                    int j = r * NT + tid + d;
                    if (r < PPT - 1 || j < S_CT)
                        m[r] = fmaxf(m[r], w[r] * xb[j]);
                }
            }
        } else {
            #pragma unroll
            for (int r = 0; r < PPT; ++r) w[r] = xb[r * NT + tid];
            for (int d = 0; d <= limit; ++d) {
                #pragma unroll
                for (int r = 0; r < PPT; ++r) {
                    int k = r * NT + tid - d;
                    if (r > 0 || k >= 0)
                        m[r] = fmaxf(m[r], xa[k] * w[r]);
                }
            }
        }
        #pragma unroll
        for (int r = 0; r < PPT; ++r) {
            int i = r * NT + tid;
            if (m[r] > best) { best = m[r]; bi = i; }
        }
    }

    // ---- wave (val,idx) butterfly reduce; lower index wins fp-equal ties ----
    #pragma unroll
    for (int s = 32; s > 0; s >>= 1) {
        float v2 = __shfl_xor(best, s);
        int i2 = __shfl_xor(bi, s);
        if (v2 > best || (v2 == best && i2 < bi)) { best = v2; bi = i2; }
    }
    __shared__ float swv[NT / 64];
    __shared__ int swi[NT / 64];
    const int wave = tid >> 6;
    if ((tid & 63) == 0) { swv[wave] = best; swi[wave] = bi; }
    __syncthreads();
    if (tid == 0) {
        #pragma unroll
        for (int k = 1; k < NT / 64; ++k) {
            if (swv[k] > best || (swv[k] == best && swi[k] < bi)) { best = swv[k]; bi = swi[k]; }
        }
        out[(size_t)path * B + b] = (float)bi;
    }
}

extern "C" void kernel_launch(void* const* d_in, const int* in_sizes, int n_in,
                              void* d_out, int out_size, void* d_ws, size_t ws_size,
                              hipStream_t stream) {
    const float* x1 = (const float*)d_in[0];
    const float* x2 = (const float*)d_in[1];
    const int* limit = (const int*)d_in[2];
    float* out = (float*)d_out;
    const int B = in_sizes[0] / S_CT;  // 32

    qa_fused_kernel<<<B * 2, NT, 0, stream>>>(x1, x2, limit, out, B);
}